// Round 12
// baseline (3903.041 us; speedup 1.0000x reference)
//
#include <hip/hip_runtime.h>

typedef short bf16x8 __attribute__((ext_vector_type(8)));
typedef float f32x4  __attribute__((ext_vector_type(4)));
typedef unsigned int u32;
typedef unsigned long long u64;

constexpr int BB = 64;     // batch
constexpr int TT = 1024;   // seq len
constexpr int DD = 64;     // input dim
constexpr int HH = 512;    // hidden
constexpr int NGRP = 8;    // groups; gb = wg & 7 -> same XCD under round-robin
constexpr int WPG  = 16;   // workgroups per group; wid = wg >> 3 owns slice wid
constexpr int NSB  = 2;    // sub-batches interleaved to hide propagation latency
constexpr int MB   = 4;    // batch rows per sub-batch (8 per group total)
constexpr int UPW  = 32;   // hidden units per wg
constexpr int BLOCK = 384; // 6 waves, one 16-col gate tile per wave

// tagged board per (buf, sub-batch, group): [row 4][pair 256] u64
// u32 word = (tag16 << 16) | bf16(h); pair = wid*16+lp covers units (2lp, 2lp+1)
constexpr size_t SLAB_U64  = (size_t)MB * 256;                 // 1024
constexpr size_t BOARD_U64 = 2 * NSB * NGRP * SLAB_U64;        // 32768
constexpr size_t BOARD_B   = BOARD_U64 * 8;                    // 256 KB

__device__ __forceinline__ size_t slab(int buf, int s, int g) {
    return ((size_t)(buf * NSB + s) * NGRP + g) * SLAB_U64;
}

__device__ __forceinline__ short f2bf(float f) {
    unsigned u = __builtin_bit_cast(unsigned, f);
    u = (u + 0x7FFFu + ((u >> 16) & 1u)) >> 16;   // round-to-nearest-even
    return (short)u;
}
__device__ __forceinline__ float bf2f(short s) {
    unsigned u = ((unsigned)(unsigned short)s) << 16;
    return __builtin_bit_cast(float, u);
}

// LDS board: [slice 16][row 4][LROW bytes]; unit ul of a slice-row at byte ul*2
constexpr int LROW = 80;
constexpr int LKK  = 336;   // 4*80 + 16 pad

__global__ __launch_bounds__(BLOCK, 2)
void gru_persistent(const float* __restrict__ x,
                    const float* __restrict__ h0,
                    const float* __restrict__ w_ih,
                    const float* __restrict__ w_hh,
                    const float* __restrict__ fc_w,
                    const float* __restrict__ fc_b,
                    float* __restrict__ out,
                    u64* __restrict__ board)
{
    const int wg   = blockIdx.x;     // 0..127
    const int gb   = wg & 7;         // group; == XCD id under round-robin dispatch
    const int wid  = wg >> 3;        // unit-wg 0..15 (owns k-slice kk == wid)
    const int tid  = threadIdx.x;
    const int wave = tid >> 6;       // 0..5
    const int lane = tid & 63;
    const int l15  = lane & 15;
    const int lhi  = lane >> 4;      // 0..3
    const int u0   = wid * UPW;

    // wave owns gate cols [wave*16, wave*16+16) of 96 = r|z|n x 32
    const int cloc = wave * 16 + l15;
    const int grow = (cloc >> 5) * HH + u0 + (cloc & 31);

    __shared__ char  lds_board[16 * LKK];   // staged h slab (A-operand + fc input)
    __shared__ float lds_gi[4][100];
    __shared__ float lds_gh[4][100];
    __shared__ float fcw_lds[HH];           // full fc_w row (f32)

    // ---- register-resident weights as MFMA B-frags, bf16 hi/lo split ----
    bf16x8 whh_hi[16], whh_lo[16];
#pragma unroll
    for (int kk = 0; kk < 16; ++kk) {
        const float* src = w_hh + (size_t)grow * HH + kk * 32 + lhi * 8;
        bf16x8 hi, lo;
#pragma unroll
        for (int i = 0; i < 8; ++i) {
            float w = src[i];
            short h16 = f2bf(w);
            hi[i] = h16; lo[i] = f2bf(w - bf2f(h16));
        }
        whh_hi[kk] = hi; whh_lo[kk] = lo;
    }
    bf16x8 wih_hi[2], wih_lo[2];
#pragma unroll
    for (int kk = 0; kk < 2; ++kk) {
        const float* src = w_ih + (size_t)grow * DD + kk * 32 + lhi * 8;
        bf16x8 hi, lo;
#pragma unroll
        for (int i = 0; i < 8; ++i) {
            float w = src[i];
            short h16 = f2bf(w);
            hi[i] = h16; lo[i] = f2bf(w - bf2f(h16));
        }
        wih_hi[kk] = hi; wih_lo[kk] = lo;
    }

    for (int i = tid; i < HH; i += BLOCK) fcw_lds[i] = fc_w[i];
    const float fcb = fc_b[0];

    // ---- init: hreg (1 unit/thread per sub-batch) + board buf0 (tag=1) ----
    float hreg[NSB] = {0.f, 0.f};
    if (tid < 128) {
        int row = tid >> 5, uu = tid & 31;
#pragma unroll
        for (int s = 0; s < NSB; ++s) {
            float hv = h0[(size_t)(gb * 8 + s * MB + row) * HH + u0 + uu];
            hreg[s] = hv;
            u32 w = (1u << 16) | (u32)(unsigned short)f2bf(hv);
            u32* bw = (u32*)(board + slab(0, s, gb)) + row * 512 + wid * 32 + uu;
            __hip_atomic_store(bw, w, __ATOMIC_RELAXED, __HIP_MEMORY_SCOPE_AGENT);
        }
    }
    __syncthreads();

    const float* xrow[NSB];
#pragma unroll
    for (int s = 0; s < NSB; ++s)
        xrow[s] = x + ((size_t)(gb * 8 + s * MB + (l15 & 3)) * TT) * DD + lhi * 8;

    // software-pipelined board reads: v holds loads for the half being verified
    u64 v[4];
    const u64* sp = board + slab(0, 0, gb) + tid;
    if (tid < 256) {
#pragma unroll
        for (int i = 0; i < 4; ++i)
            v[i] = __hip_atomic_load(sp + (size_t)i * 256,
                                     __ATOMIC_RELAXED, __HIP_MEMORY_SCOPE_AGENT);
    }

    for (int t = 0; t <= TT; ++t) {
#pragma unroll
        for (int s = 0; s < NSB; ++s) {
            const int wbuf = (t & 1) ^ 1;

            // (a) gi = x_t @ w_ih^T for this sub-batch (skip on epilogue)
            f32x4 acc_gi = {0.f, 0.f, 0.f, 0.f};
            if (t < TT) {
                f32x4 gih = {0.f,0.f,0.f,0.f}, gil = {0.f,0.f,0.f,0.f};
#pragma unroll
                for (int kk = 0; kk < 2; ++kk) {
                    const float* xs = xrow[s] + (size_t)t * DD + kk * 32;
                    const float4 v0 = *(const float4*)(xs);
                    const float4 v1 = *(const float4*)(xs + 4);
                    bf16x8 a;
                    a[0] = f2bf(v0.x); a[1] = f2bf(v0.y); a[2] = f2bf(v0.z); a[3] = f2bf(v0.w);
                    a[4] = f2bf(v1.x); a[5] = f2bf(v1.y); a[6] = f2bf(v1.z); a[7] = f2bf(v1.w);
                    gih = __builtin_amdgcn_mfma_f32_16x16x32_bf16(a, wih_hi[kk], gih, 0, 0, 0);
                    gil = __builtin_amdgcn_mfma_f32_16x16x32_bf16(a, wih_lo[kk], gil, 0, 0, 0);
                }
                acc_gi = gih + gil;
            }

            // (b) sound verify of prefetched v; reload-all on stale; unpack
            if (tid < 256) {
                const u32 expTag = (u32)(t + 1) << 16;
                while (true) {
                    u32 bad = 0;
#pragma unroll
                    for (int i = 0; i < 4; ++i) {
                        u32 lo = (u32)v[i], hi = (u32)(v[i] >> 32);
                        bad |= ((lo ^ expTag) | (hi ^ expTag)) & 0xFFFF0000u;
                    }
                    if (!__any(bad != 0)) break;
#pragma unroll
                    for (int i = 0; i < 4; ++i)
                        v[i] = __hip_atomic_load(sp + (size_t)i * 256,
                                                 __ATOMIC_RELAXED, __HIP_MEMORY_SCOPE_AGENT);
                }
                char* lb = lds_board + (tid >> 4) * LKK + (tid & 15) * 4;
#pragma unroll
                for (int i = 0; i < 4; ++i) {
                    u32 d = __builtin_amdgcn_perm((u32)(v[i] >> 32), (u32)v[i], 0x05040100u);
                    *(u32*)(lb + i * LROW) = d;
                }
            }
            __syncthreads();

            // (c) prefetch the NEXT half's slab (RT hides under MFMA+gates)
            {
                const int ns = s ^ 1;
                const int nt = (s == 1) ? t + 1 : t;
                if (nt <= TT) {
                    sp = board + slab(nt & 1, ns, gb) + tid;
                    if (tid < 256) {
#pragma unroll
                        for (int i = 0; i < 4; ++i)
                            v[i] = __hip_atomic_load(sp + (size_t)i * 256,
                                                     __ATOMIC_RELAXED, __HIP_MEMORY_SCOPE_AGENT);
                    }
                }
            }

            // (d) fc out[row, t-1] for this sub-batch's rows (plain store)
            {
                const int rs = wid - s * MB;
                if (wave == 0 && (unsigned)rs < (unsigned)MB && t >= 1) {
                    const char* lb = lds_board + (lane >> 2) * LKK + rs * LROW + (lane & 3) * 16;
                    bf16x8 hv = *(const bf16x8*)lb;
                    float ss = 0.f;
#pragma unroll
                    for (int i = 0; i < 8; ++i)
                        ss += fmaxf(bf2f(hv[i]), 0.f) * fcw_lds[lane * 8 + i];
#pragma unroll
                    for (int off = 1; off < 64; off <<= 1) ss += __shfl_xor(ss, off, 64);
                    if (lane == 0)
                        out[(size_t)(gb * 8 + s * MB + rs) * TT + (t - 1)] = ss + fcb;
                }
            }
            if (t == TT) continue;   // epilogue half: fc only

            // (e) gh MFMAs from LDS A-frags (A rows = l15&3, dup above row 3)
            f32x4 ghh = {0.f,0.f,0.f,0.f}, ghl = {0.f,0.f,0.f,0.f};
            {
                const char* la = lds_board + (l15 & 3) * LROW + lhi * 16;
#pragma unroll
                for (int kk = 0; kk < 16; ++kk) {
                    bf16x8 a = *(const bf16x8*)(la + kk * LKK);
                    ghh = __builtin_amdgcn_mfma_f32_16x16x32_bf16(a, whh_hi[kk], ghh, 0, 0, 0);
                    ghl = __builtin_amdgcn_mfma_f32_16x16x32_bf16(a, whh_lo[kk], ghl, 0, 0, 0);
                }
            }
            f32x4 acc_gh = ghh + ghl;

            // (f) C/D -> LDS: rows 0..3 live in lhi==0 lanes (row = j)
            if (lhi == 0) {
#pragma unroll
                for (int j = 0; j < 4; ++j) {
                    lds_gi[j][cloc] = acc_gi[j];
                    lds_gh[j][cloc] = acc_gh[j];
                }
            }
            __syncthreads();

            // (g) gates + h update + immediate tagged publish (1 unit/thread)
            if (tid < 128) {
                const u32 tagNew = (u32)(t + 2) << 16;
                int row = tid >> 5, uu = tid & 31;
                float gr  = lds_gi[row][uu]      + lds_gh[row][uu];
                float gz  = lds_gi[row][32 + uu] + lds_gh[row][32 + uu];
                float gin = lds_gi[row][64 + uu];
                float ghn = lds_gh[row][64 + uu];
                float r = 1.f / (1.f + __expf(-gr));
                float z = 1.f / (1.f + __expf(-gz));
                float vv = gin + r * ghn;
                vv = fminf(15.f, fmaxf(-15.f, vv));
                float e2 = __expf(-2.f * vv);
                float n = (1.f - e2) / (1.f + e2);           // tanh
                float hn = (1.f - z) * n + z * hreg[s];
                hreg[s] = hn;
                u32 w = tagNew | (u32)(unsigned short)f2bf(hn);
                u32* bw = (u32*)(board + slab(wbuf, s, gb)) + row * 512 + wid * 32 + uu;
                __hip_atomic_store(bw, w, __ATOMIC_RELAXED, __HIP_MEMORY_SCOPE_AGENT);
                if (t == TT - 1)
                    out[(size_t)BB * TT + (size_t)(gb * 8 + s * MB + row) * HH + u0 + uu] = hn;
            }
            // no trailing barrier: next half's post-unpack barrier orders LDS reuse
        }
    }
}

extern "C" void kernel_launch(void* const* d_in, const int* in_sizes, int n_in,
                              void* d_out, int out_size, void* d_ws, size_t ws_size,
                              hipStream_t stream)
{
    const float* x    = (const float*)d_in[0];
    const float* h0   = (const float*)d_in[1];
    const float* w_ih = (const float*)d_in[2];
    const float* w_hh = (const float*)d_in[3];
    const float* fc_w = (const float*)d_in[4];
    const float* fc_b = (const float*)d_in[5];
    float* out = (float*)d_out;
    u64* board = (u64*)d_ws;

    // clear board tags so every replay re-synchronizes from scratch
    // (out needs no memset: every element is written by exactly one plain store)
    hipMemsetAsync(d_ws, 0, BOARD_B, stream);

    void* args[] = { (void*)&x, (void*)&h0, (void*)&w_ih, (void*)&w_hh,
                     (void*)&fc_w, (void*)&fc_b, (void*)&out, (void*)&board };
    hipError_t err = hipLaunchCooperativeKernel((void*)gru_persistent,
                                                dim3(NGRP * WPG), dim3(BLOCK),
                                                args, 0, stream);
    if (err != hipSuccess) {
        (void)hipGetLastError();  // clear sticky error; plain launch (128 blocks
        // at 2 blocks/CU occupancy are trivially co-resident on 256 CUs)
        gru_persistent<<<dim3(NGRP * WPG), dim3(BLOCK), 0, stream>>>(
            x, h0, w_ih, w_hh, fc_w, fc_b, out, board);
    }
}

// Round 13
// 3469.527 us; speedup vs baseline: 1.1249x; 1.1249x over previous
//
#include <hip/hip_runtime.h>

typedef short bf16x8 __attribute__((ext_vector_type(8)));
typedef float f32x4  __attribute__((ext_vector_type(4)));
typedef unsigned int u32;
typedef unsigned long long u64;

constexpr int BB = 64;     // batch
constexpr int TT = 1024;   // seq len
constexpr int DD = 64;     // input dim
constexpr int HH = 512;    // hidden
constexpr int NGRP = 8;    // groups; gb = wg & 7 -> same XCD under round-robin
constexpr int WPG  = 16;   // workgroups per group; wid = wg >> 3 owns slice wid
constexpr int MB   = 8;    // batch rows per group
constexpr int UPW  = 32;   // hidden units per wg
constexpr int BLOCK = 384; // 6 waves, one 16-col gate tile per wave

// tagged board: [2][NGRP][row 8][pair 256] u64; u64 = two tagged words
// word = (tag16 << 16) | bf16(h); pair index = wid*16+lp covers units (2lp,2lp+1)
constexpr size_t SLAB_U64  = (size_t)MB * 256;            // 2048 u64 per (buf,grp)
constexpr size_t BOARD_U64 = 2 * NGRP * SLAB_U64;         // 32768 u64
constexpr size_t BOARD_B   = BOARD_U64 * 8;               // 256 KB

__device__ __forceinline__ short f2bf(float f) {
    unsigned u = __builtin_bit_cast(unsigned, f);
    u = (u + 0x7FFFu + ((u >> 16) & 1u)) >> 16;   // round-to-nearest-even
    return (short)u;
}
__device__ __forceinline__ float bf2f(short s) {
    unsigned u = ((unsigned)(unsigned short)s) << 16;
    return __builtin_bit_cast(float, u);
}

// dual publish: sc0 store -> same-XCD L2 (fast path, ~200-300 cy visibility);
// agent atomic store -> coherence point (liveness for any misplaced consumer)
__device__ __forceinline__ void publish64(u64* p, u64 v) {
    asm volatile("global_store_dwordx2 %0, %1, off sc0" :: "v"(p), "v"(v) : "memory");
    __hip_atomic_store(p, v, __ATOMIC_RELAXED, __HIP_MEMORY_SCOPE_AGENT);
}

// LDS board: [slice 16][row 8][LROW bytes]; unit ul of a slice-row at byte ul*2
constexpr int LROW = 80;
constexpr int LKK  = 656;   // 8*80 + 16 pad

__global__ __launch_bounds__(BLOCK, 2)
void gru_persistent(const float* __restrict__ x,
                    const float* __restrict__ h0,
                    const float* __restrict__ w_ih,
                    const float* __restrict__ w_hh,
                    const float* __restrict__ fc_w,
                    const float* __restrict__ fc_b,
                    float* __restrict__ out,
                    u64* __restrict__ board)
{
    const int wg   = blockIdx.x;     // 0..127
    const int gb   = wg & 7;         // group; == XCD id under round-robin dispatch
    const int wid  = wg >> 3;        // unit-wg 0..15 (owns k-slice kk == wid)
    const int tid  = threadIdx.x;
    const int wave = tid >> 6;       // 0..5
    const int lane = tid & 63;
    const int l15  = lane & 15;
    const int lhi  = lane >> 4;      // 0..3
    const int u0   = wid * UPW;

    // wave owns gate cols [wave*16, wave*16+16) of 96 = r|z|n x 32
    const int cloc = wave * 16 + l15;
    const int grow = (cloc >> 5) * HH + u0 + (cloc & 31);

    __shared__ char  lds_board[16 * LKK];   // staged h slab (A-operand + fc input)
    __shared__ float lds_gi[8][100];
    __shared__ float lds_gh[8][100];
    __shared__ float fcw_lds[HH];           // full fc_w row (f32)

    // ---- register-resident weights as MFMA B-frags, bf16 hi/lo split ----
    bf16x8 whh_hi[16], whh_lo[16];
#pragma unroll
    for (int kk = 0; kk < 16; ++kk) {
        const float* src = w_hh + (size_t)grow * HH + kk * 32 + lhi * 8;
        bf16x8 hi, lo;
#pragma unroll
        for (int i = 0; i < 8; ++i) {
            float w = src[i];
            short h16 = f2bf(w);
            hi[i] = h16; lo[i] = f2bf(w - bf2f(h16));
        }
        whh_hi[kk] = hi; whh_lo[kk] = lo;
    }
    bf16x8 wih_hi[2], wih_lo[2];
#pragma unroll
    for (int kk = 0; kk < 2; ++kk) {
        const float* src = w_ih + (size_t)grow * DD + kk * 32 + lhi * 8;
        bf16x8 hi, lo;
#pragma unroll
        for (int i = 0; i < 8; ++i) {
            float w = src[i];
            short h16 = f2bf(w);
            hi[i] = h16; lo[i] = f2bf(w - bf2f(h16));
        }
        wih_hi[kk] = hi; wih_lo[kk] = lo;
    }

    for (int i = tid; i < HH; i += BLOCK) fcw_lds[i] = fc_w[i];
    const float fcb = fc_b[0];

    // ---- init: hreg (2 f32/thread, tid<128) + board buf0 tagged (tag=1) ----
    float hreg0 = 0.f, hreg1 = 0.f;
    if (tid < 128) {
        int row = tid >> 4, lp = tid & 15;
        hreg0 = h0[(size_t)(gb * MB + row) * HH + (u0 + 2 * lp)];
        hreg1 = h0[(size_t)(gb * MB + row) * HH + (u0 + 2 * lp + 1)];
        u32 wa = (1u << 16) | (u32)(unsigned short)f2bf(hreg0);
        u32 wb = (1u << 16) | (u32)(unsigned short)f2bf(hreg1);
        u64* bw = board + (size_t)(0 * NGRP + gb) * SLAB_U64 + row * 256 + (wid * 16 + lp);
        publish64(bw, (u64)wa | ((u64)wb << 32));
    }
    __syncthreads();

    const float* xrow = x + ((size_t)(gb * MB + (l15 & 7)) * TT) * DD + lhi * 8;

    for (int t = 0; t <= TT; ++t) {
        const int rbuf = t & 1, wbuf = rbuf ^ 1;

        // (a) issue the speculative sc0 board read FIRST (no wait yet;
        //     the L2 round trip overlaps the gi MFMAs below)
        u64 v[8];
        const u64* sp = board + (size_t)(rbuf * NGRP + gb) * SLAB_U64 + tid;
        if (tid < 256) {
            asm volatile(
                "global_load_dwordx2 %[o0], %[p0], off sc0\n\t"
                "global_load_dwordx2 %[o1], %[p1], off sc0\n\t"
                "global_load_dwordx2 %[o2], %[p2], off sc0\n\t"
                "global_load_dwordx2 %[o3], %[p3], off sc0\n\t"
                "global_load_dwordx2 %[o4], %[p4], off sc0\n\t"
                "global_load_dwordx2 %[o5], %[p5], off sc0\n\t"
                "global_load_dwordx2 %[o6], %[p6], off sc0\n\t"
                "global_load_dwordx2 %[o7], %[p7], off sc0"
                : [o0]"=&v"(v[0]), [o1]"=&v"(v[1]), [o2]"=&v"(v[2]), [o3]"=&v"(v[3]),
                  [o4]"=&v"(v[4]), [o5]"=&v"(v[5]), [o6]"=&v"(v[6]), [o7]"=&v"(v[7])
                : [p0]"v"(sp),        [p1]"v"(sp + 256),  [p2]"v"(sp + 512),
                  [p3]"v"(sp + 768),  [p4]"v"(sp + 1024), [p5]"v"(sp + 1280),
                  [p6]"v"(sp + 1536), [p7]"v"(sp + 1792)
                : "memory");
        }

        // (b) gi = x_t @ w_ih^T (skip on the epilogue iteration)
        f32x4 acc_gi = {0.f, 0.f, 0.f, 0.f};
        if (t < TT) {
            f32x4 gi_hi = {0.f,0.f,0.f,0.f}, gi_lo = {0.f,0.f,0.f,0.f};
#pragma unroll
            for (int kk = 0; kk < 2; ++kk) {
                const float* xs = xrow + (size_t)t * DD + kk * 32;
                const float4 v0 = *(const float4*)(xs);
                const float4 v1 = *(const float4*)(xs + 4);
                bf16x8 a;
                a[0] = f2bf(v0.x); a[1] = f2bf(v0.y); a[2] = f2bf(v0.z); a[3] = f2bf(v0.w);
                a[4] = f2bf(v1.x); a[5] = f2bf(v1.y); a[6] = f2bf(v1.z); a[7] = f2bf(v1.w);
                gi_hi = __builtin_amdgcn_mfma_f32_16x16x32_bf16(a, wih_hi[kk], gi_hi, 0, 0, 0);
                gi_lo = __builtin_amdgcn_mfma_f32_16x16x32_bf16(a, wih_lo[kk], gi_lo, 0, 0, 0);
            }
            acc_gi = gi_hi + gi_lo;
        }

        // (c) wait for the prefetch, sound verify; stale -> <=4 sc0 retry rounds
        //     (same-XCD L2 RT), then the guaranteed agent-atomic path (R11)
        if (tid < 256) {
            asm volatile("s_waitcnt vmcnt(0)" ::: "memory");
            __builtin_amdgcn_sched_barrier(0);
            const u32 expTag = (u32)(t + 1) << 16;
            int tries = 0;
            while (true) {
                u32 bad = 0;
#pragma unroll
                for (int i = 0; i < 8; ++i) {
                    u32 lo = (u32)v[i], hi = (u32)(v[i] >> 32);
                    bad |= ((lo ^ expTag) | (hi ^ expTag)) & 0xFFFF0000u;
                }
                if (!__any(bad != 0)) break;
                if (++tries <= 4) {
                    asm volatile(
                        "global_load_dwordx2 %[o0], %[p0], off sc0\n\t"
                        "global_load_dwordx2 %[o1], %[p1], off sc0\n\t"
                        "global_load_dwordx2 %[o2], %[p2], off sc0\n\t"
                        "global_load_dwordx2 %[o3], %[p3], off sc0\n\t"
                        "global_load_dwordx2 %[o4], %[p4], off sc0\n\t"
                        "global_load_dwordx2 %[o5], %[p5], off sc0\n\t"
                        "global_load_dwordx2 %[o6], %[p6], off sc0\n\t"
                        "global_load_dwordx2 %[o7], %[p7], off sc0\n\t"
                        "s_waitcnt vmcnt(0)"
                        : [o0]"=&v"(v[0]), [o1]"=&v"(v[1]), [o2]"=&v"(v[2]), [o3]"=&v"(v[3]),
                          [o4]"=&v"(v[4]), [o5]"=&v"(v[5]), [o6]"=&v"(v[6]), [o7]"=&v"(v[7])
                        : [p0]"v"(sp),        [p1]"v"(sp + 256),  [p2]"v"(sp + 512),
                          [p3]"v"(sp + 768),  [p4]"v"(sp + 1024), [p5]"v"(sp + 1280),
                          [p6]"v"(sp + 1536), [p7]"v"(sp + 1792)
                        : "memory");
                    __builtin_amdgcn_sched_barrier(0);
                } else {
#pragma unroll
                    for (int i = 0; i < 8; ++i)
                        v[i] = __hip_atomic_load(sp + (size_t)i * 256,
                                                 __ATOMIC_RELAXED, __HIP_MEMORY_SCOPE_AGENT);
                }
            }
            // unpack to LDS: slice kk = tid>>4, pair lp = tid&15, rows i
            char* lb = lds_board + (tid >> 4) * LKK + (tid & 15) * 4;
#pragma unroll
            for (int i = 0; i < 8; ++i) {
                u32 d = __builtin_amdgcn_perm((u32)(v[i] >> 32), (u32)v[i], 0x05040100u);
                *(u32*)(lb + i * LROW) = d;
            }
        }
        __syncthreads();

        // (d) fc output for step t-1: WGs wid<8 own batch row wid; wave 0 does
        // the full 512-unit dot from the staged slab (plain store, NO atomics)
        if (wave == 0 && wid < MB && t >= 1) {
            const char* lb = lds_board + (lane >> 2) * LKK + wid * LROW + (lane & 3) * 16;
            bf16x8 hv = *(const bf16x8*)lb;
            float s = 0.f;
#pragma unroll
            for (int i = 0; i < 8; ++i)
                s += fmaxf(bf2f(hv[i]), 0.f) * fcw_lds[lane * 8 + i];
#pragma unroll
            for (int off = 1; off < 64; off <<= 1) s += __shfl_xor(s, off, 64);
            if (lane == 0)
                out[(size_t)(gb * MB + wid) * TT + (t - 1)] = s + fcb;
        }
        if (t == TT) break;   // epilogue: only out[TT-1] remained

        // (e) gh MFMAs from LDS A-frags (rows dup for l15 in 8..15)
        f32x4 gh_hi = {0.f,0.f,0.f,0.f}, gh_lo = {0.f,0.f,0.f,0.f};
        {
            const char* la = lds_board + (l15 & 7) * LROW + lhi * 16;
#pragma unroll
            for (int kk = 0; kk < 16; ++kk) {
                bf16x8 a = *(const bf16x8*)(la + kk * LKK);
                gh_hi = __builtin_amdgcn_mfma_f32_16x16x32_bf16(a, whh_hi[kk], gh_hi, 0, 0, 0);
                gh_lo = __builtin_amdgcn_mfma_f32_16x16x32_bf16(a, whh_lo[kk], gh_lo, 0, 0, 0);
            }
        }
        f32x4 acc_gh = gh_hi + gh_lo;

        // (f) C/D -> LDS: col = cloc, row = lhi*4 + j (rows 0..7 only)
        if (lhi < 2) {
#pragma unroll
            for (int j = 0; j < 4; ++j) {
                int row = lhi * 4 + j;
                lds_gi[row][cloc] = acc_gi[j];
                lds_gh[row][cloc] = acc_gh[j];
            }
        }
        __syncthreads();

        // (g) gates + h update + immediate dual publish (2 units/thread)
        if (tid < 128) {
            const u32 tagNew = (u32)(t + 2) << 16;
            int row = tid >> 4, lp = tid & 15;
            int uu0 = 2 * lp, uu1 = uu0 + 1;
            float hn01[2];
            float hp[2] = {hreg0, hreg1};
#pragma unroll
            for (int q = 0; q < 2; ++q) {
                int uu = uu0 + q;
                float gr  = lds_gi[row][uu]      + lds_gh[row][uu];
                float gz  = lds_gi[row][32 + uu] + lds_gh[row][32 + uu];
                float gin = lds_gi[row][64 + uu];
                float ghn = lds_gh[row][64 + uu];
                float r = 1.f / (1.f + __expf(-gr));
                float z = 1.f / (1.f + __expf(-gz));
                float vv = gin + r * ghn;
                vv = fminf(15.f, fmaxf(-15.f, vv));
                float e2 = __expf(-2.f * vv);
                float n = (1.f - e2) / (1.f + e2);           // tanh
                hn01[q] = (1.f - z) * n + z * hp[q];
            }
            hreg0 = hn01[0]; hreg1 = hn01[1];
            // publish FIRST (critical path for the 15 peers)
            u32 wa = tagNew | (u32)(unsigned short)f2bf(hn01[0]);
            u32 wb = tagNew | (u32)(unsigned short)f2bf(hn01[1]);
            u64* bw = board + (size_t)(wbuf * NGRP + gb) * SLAB_U64
                    + row * 256 + (wid * 16 + lp);
            publish64(bw, (u64)wa | ((u64)wb << 32));
            if (t == TT - 1) {
                out[(size_t)BB * TT + (size_t)(gb * MB + row) * HH + (u0 + uu0)] = hn01[0];
                out[(size_t)BB * TT + (size_t)(gb * MB + row) * HH + (u0 + uu1)] = hn01[1];
            }
        }
        // no barrier needed here: (c)'s barrier in the next iteration orders
        // lds_board rewrites; lds_gi/gh rewrites are behind the same barrier
    }
}

extern "C" void kernel_launch(void* const* d_in, const int* in_sizes, int n_in,
                              void* d_out, int out_size, void* d_ws, size_t ws_size,
                              hipStream_t stream)
{
    const float* x    = (const float*)d_in[0];
    const float* h0   = (const float*)d_in[1];
    const float* w_ih = (const float*)d_in[2];
    const float* w_hh = (const float*)d_in[3];
    const float* fc_w = (const float*)d_in[4];
    const float* fc_b = (const float*)d_in[5];
    float* out = (float*)d_out;
    u64* board = (u64*)d_ws;

    // clear board tags so every replay re-synchronizes from scratch
    // (out needs no memset: every element is written by exactly one plain store)
    hipMemsetAsync(d_ws, 0, BOARD_B, stream);

    void* args[] = { (void*)&x, (void*)&h0, (void*)&w_ih, (void*)&w_hh,
                     (void*)&fc_w, (void*)&fc_b, (void*)&out, (void*)&board };
    hipError_t err = hipLaunchCooperativeKernel((void*)gru_persistent,
                                                dim3(NGRP * WPG), dim3(BLOCK),
                                                args, 0, stream);
    if (err != hipSuccess) {
        (void)hipGetLastError();  // clear sticky error; plain launch (128 blocks
        // at 2 blocks/CU occupancy are trivially co-resident on 256 CUs)
        gru_persistent<<<dim3(NGRP * WPG), dim3(BLOCK), 0, stream>>>(
            x, h0, w_ih, w_hh, fc_w, fc_b, out, board);
    }
}

// Round 14
// 2886.864 us; speedup vs baseline: 1.3520x; 1.2018x over previous
//
#include <hip/hip_runtime.h>

typedef short bf16x8 __attribute__((ext_vector_type(8)));
typedef float f32x4  __attribute__((ext_vector_type(4)));
typedef unsigned int u32;
typedef unsigned long long u64;

constexpr int BB = 64;     // batch
constexpr int TT = 1024;   // seq len
constexpr int DD = 64;     // input dim
constexpr int HH = 512;    // hidden
constexpr int NGRP = 8;    // batch groups; group = wg & 7 -> same XCD under
                           // round-robin dispatch (heuristic only, not required)
constexpr int WPG  = 16;   // workgroups per group; wid = wg >> 3 owns slice wid
constexpr int MB   = 8;    // batch rows per group
constexpr int UPW  = 32;   // hidden units per wg
constexpr int BLOCK = 384; // 6 waves, one 16-col gate tile per wave

// tagged board: [2][NGRP][row 8][pair 256] u64; u64 = two tagged words
// word = (tag16 << 16) | bf16(h); pair index = wid*16+lp covers units (2lp,2lp+1)
constexpr size_t SLAB_U64  = (size_t)MB * 256;            // 2048 u64 per (buf,grp)
constexpr size_t BOARD_U64 = 2 * NGRP * SLAB_U64;         // 32768 u64
constexpr size_t BOARD_B   = BOARD_U64 * 8;               // 256 KB

__device__ __forceinline__ short f2bf(float f) {
    unsigned u = __builtin_bit_cast(unsigned, f);
    u = (u + 0x7FFFu + ((u >> 16) & 1u)) >> 16;   // round-to-nearest-even
    return (short)u;
}
__device__ __forceinline__ float bf2f(short s) {
    unsigned u = ((unsigned)(unsigned short)s) << 16;
    return __builtin_bit_cast(float, u);
}

// LDS board: [kk 16][row 8][LROW bytes]; unit ul of a slice-row at byte ul*2
constexpr int LROW = 80;
constexpr int LKK  = 656;   // 8*80 + 16 pad

__global__ __launch_bounds__(BLOCK, 2)
void gru_persistent(const float* __restrict__ x,
                    const float* __restrict__ h0,
                    const float* __restrict__ w_ih,
                    const float* __restrict__ w_hh,
                    const float* __restrict__ fc_w,
                    const float* __restrict__ fc_b,
                    float* __restrict__ out,
                    u64* __restrict__ board)
{
    const int wg   = blockIdx.x;     // 0..127
    const int gb   = wg & 7;         // group; == XCD id under round-robin dispatch
    const int wid  = wg >> 3;        // unit-wg 0..15 (owns k-slice kk == wid)
    const int tid  = threadIdx.x;
    const int wave = tid >> 6;       // 0..5
    const int lane = tid & 63;
    const int l15  = lane & 15;
    const int lhi  = lane >> 4;      // 0..3
    const int u0   = wid * UPW;

    // wave owns gate cols [wave*16, wave*16+16) of 96 = r|z|n x 32
    const int cloc = wave * 16 + l15;
    const int grow = (cloc >> 5) * HH + u0 + (cloc & 31);

    __shared__ char  lds_board[16 * LKK];   // staged h slab (A-operand + fc input)
    __shared__ float lds_gi[8][100];
    __shared__ float lds_gh[8][100];
    __shared__ float fcw_lds[HH];           // full fc_w row (f32)

    // ---- register-resident weights as MFMA B-frags, bf16 hi/lo split ----
    bf16x8 whh_hi[16], whh_lo[16];
#pragma unroll
    for (int kk = 0; kk < 16; ++kk) {
        const float* src = w_hh + (size_t)grow * HH + kk * 32 + lhi * 8;
        bf16x8 hi, lo;
#pragma unroll
        for (int i = 0; i < 8; ++i) {
            float w = src[i];
            short h16 = f2bf(w);
            hi[i] = h16; lo[i] = f2bf(w - bf2f(h16));
        }
        whh_hi[kk] = hi; whh_lo[kk] = lo;
    }
    bf16x8 wih_hi[2], wih_lo[2];
#pragma unroll
    for (int kk = 0; kk < 2; ++kk) {
        const float* src = w_ih + (size_t)grow * DD + kk * 32 + lhi * 8;
        bf16x8 hi, lo;
#pragma unroll
        for (int i = 0; i < 8; ++i) {
            float w = src[i];
            short h16 = f2bf(w);
            hi[i] = h16; lo[i] = f2bf(w - bf2f(h16));
        }
        wih_hi[kk] = hi; wih_lo[kk] = lo;
    }

    for (int i = tid; i < HH; i += BLOCK) fcw_lds[i] = fc_w[i];
    const float fcb = fc_b[0];

    // ---- init: hreg (2 f32/thread, tid<128) + board buf0 tagged (tag=1) ----
    float hreg0 = 0.f, hreg1 = 0.f;
    if (tid < 128) {
        int row = tid >> 4, lp = tid & 15;
        hreg0 = h0[(size_t)(gb * MB + row) * HH + (u0 + 2 * lp)];
        hreg1 = h0[(size_t)(gb * MB + row) * HH + (u0 + 2 * lp + 1)];
        u32 wa = (1u << 16) | (u32)(unsigned short)f2bf(hreg0);
        u32 wb = (1u << 16) | (u32)(unsigned short)f2bf(hreg1);
        u64* bw = board + (size_t)(0 * NGRP + gb) * SLAB_U64 + row * 256 + (wid * 16 + lp);
        __hip_atomic_store(bw, (u64)wa | ((u64)wb << 32),
                           __ATOMIC_RELAXED, __HIP_MEMORY_SCOPE_AGENT);
    }
    __syncthreads();

    const float* xrow = x + ((size_t)(gb * MB + (l15 & 7)) * TT) * DD + lhi * 8;

    for (int t = 0; t <= TT; ++t) {
        const int rbuf = t & 1, wbuf = rbuf ^ 1;

        // (a) issue the speculative board read FIRST (RT overlaps gi compute)
        u64 v[8];
        const u64* sp = board + (size_t)(rbuf * NGRP + gb) * SLAB_U64 + tid;
        if (tid < 256) {
#pragma unroll
            for (int i = 0; i < 8; ++i)
                v[i] = __hip_atomic_load(sp + (size_t)i * 256,
                                         __ATOMIC_RELAXED, __HIP_MEMORY_SCOPE_AGENT);
        }

        // (b) gi = x_t @ w_ih^T (skip on the epilogue iteration)
        f32x4 acc_gi = {0.f, 0.f, 0.f, 0.f};
        if (t < TT) {
            f32x4 gi_hi = {0.f,0.f,0.f,0.f}, gi_lo = {0.f,0.f,0.f,0.f};
#pragma unroll
            for (int kk = 0; kk < 2; ++kk) {
                const float* xs = xrow + (size_t)t * DD + kk * 32;
                const float4 v0 = *(const float4*)(xs);
                const float4 v1 = *(const float4*)(xs + 4);
                bf16x8 a;
                a[0] = f2bf(v0.x); a[1] = f2bf(v0.y); a[2] = f2bf(v0.z); a[3] = f2bf(v0.w);
                a[4] = f2bf(v1.x); a[5] = f2bf(v1.y); a[6] = f2bf(v1.z); a[7] = f2bf(v1.w);
                gi_hi = __builtin_amdgcn_mfma_f32_16x16x32_bf16(a, wih_hi[kk], gi_hi, 0, 0, 0);
                gi_lo = __builtin_amdgcn_mfma_f32_16x16x32_bf16(a, wih_lo[kk], gi_lo, 0, 0, 0);
            }
            acc_gi = gi_hi + gi_lo;
        }

        // (c) sound verify + bulk-reload spin (measured best protocol: R8->R11)
        if (tid < 256) {
            const u32 expTag = (u32)(t + 1) << 16;
            while (true) {
                u32 bad = 0;
#pragma unroll
                for (int i = 0; i < 8; ++i) {
                    u32 lo = (u32)v[i], hi = (u32)(v[i] >> 32);
                    bad |= ((lo ^ expTag) | (hi ^ expTag)) & 0xFFFF0000u;
                }
                if (!__any(bad != 0)) break;
#pragma unroll
                for (int i = 0; i < 8; ++i)
                    v[i] = __hip_atomic_load(sp + (size_t)i * 256,
                                             __ATOMIC_RELAXED, __HIP_MEMORY_SCOPE_AGENT);
            }
            // unpack to LDS: slice kk = tid>>4, pair lp = tid&15, rows i
            char* lb = lds_board + (tid >> 4) * LKK + (tid & 15) * 4;
#pragma unroll
            for (int i = 0; i < 8; ++i) {
                u32 d = __builtin_amdgcn_perm((u32)(v[i] >> 32), (u32)v[i], 0x05040100u);
                *(u32*)(lb + i * LROW) = d;
            }
        }
        __syncthreads();

        // (d) fc output for step t-1: WGs wid<8 own batch row wid; wave 0 does
        // the full 512-unit dot from the staged slab (plain store, NO atomics)
        if (wave == 0 && wid < MB && t >= 1) {
            const char* lb = lds_board + (lane >> 2) * LKK + wid * LROW + (lane & 3) * 16;
            bf16x8 hv = *(const bf16x8*)lb;
            float s = 0.f;
#pragma unroll
            for (int i = 0; i < 8; ++i)
                s += fmaxf(bf2f(hv[i]), 0.f) * fcw_lds[lane * 8 + i];
#pragma unroll
            for (int off = 1; off < 64; off <<= 1) s += __shfl_xor(s, off, 64);
            if (lane == 0)
                out[(size_t)(gb * MB + wid) * TT + (t - 1)] = s + fcb;
        }
        if (t == TT) break;   // epilogue: only out[TT-1] remained

        // (e) gh MFMAs from LDS A-frags (rows dup for l15 in 8..15)
        f32x4 gh_hi = {0.f,0.f,0.f,0.f}, gh_lo = {0.f,0.f,0.f,0.f};
        {
            const char* la = lds_board + (l15 & 7) * LROW + lhi * 16;
#pragma unroll
            for (int kk = 0; kk < 16; ++kk) {
                bf16x8 a = *(const bf16x8*)(la + kk * LKK);
                gh_hi = __builtin_amdgcn_mfma_f32_16x16x32_bf16(a, whh_hi[kk], gh_hi, 0, 0, 0);
                gh_lo = __builtin_amdgcn_mfma_f32_16x16x32_bf16(a, whh_lo[kk], gh_lo, 0, 0, 0);
            }
        }
        f32x4 acc_gh = gh_hi + gh_lo;

        // (f) C/D -> LDS: col = cloc, row = lhi*4 + j (rows 0..7 only)
        if (lhi < 2) {
#pragma unroll
            for (int j = 0; j < 4; ++j) {
                int row = lhi * 4 + j;
                lds_gi[row][cloc] = acc_gi[j];
                lds_gh[row][cloc] = acc_gh[j];
            }
        }
        __syncthreads();

        // (g) gates + h update + immediate tagged publish (2 units/thread)
        if (tid < 128) {
            const u32 tagNew = (u32)(t + 2) << 16;
            int row = tid >> 4, lp = tid & 15;
            int uu0 = 2 * lp, uu1 = uu0 + 1;
            float hn01[2];
            float hp[2] = {hreg0, hreg1};
#pragma unroll
            for (int q = 0; q < 2; ++q) {
                int uu = uu0 + q;
                float gr  = lds_gi[row][uu]      + lds_gh[row][uu];
                float gz  = lds_gi[row][32 + uu] + lds_gh[row][32 + uu];
                float gin = lds_gi[row][64 + uu];
                float ghn = lds_gh[row][64 + uu];
                float r = 1.f / (1.f + __expf(-gr));
                float z = 1.f / (1.f + __expf(-gz));
                float vv = gin + r * ghn;
                vv = fminf(15.f, fmaxf(-15.f, vv));
                float e2 = __expf(-2.f * vv);
                float n = (1.f - e2) / (1.f + e2);           // tanh
                hn01[q] = (1.f - z) * n + z * hp[q];
            }
            hreg0 = hn01[0]; hreg1 = hn01[1];
            // publish FIRST (critical path for the 15 peers)
            u32 wa = tagNew | (u32)(unsigned short)f2bf(hn01[0]);
            u32 wb = tagNew | (u32)(unsigned short)f2bf(hn01[1]);
            u64* bw = board + (size_t)(wbuf * NGRP + gb) * SLAB_U64
                    + row * 256 + (wid * 16 + lp);
            __hip_atomic_store(bw, (u64)wa | ((u64)wb << 32),
                               __ATOMIC_RELAXED, __HIP_MEMORY_SCOPE_AGENT);
            if (t == TT - 1) {
                out[(size_t)BB * TT + (size_t)(gb * MB + row) * HH + (u0 + uu0)] = hn01[0];
                out[(size_t)BB * TT + (size_t)(gb * MB + row) * HH + (u0 + uu1)] = hn01[1];
            }
        }
        // no barrier needed here: (c)'s barrier in the next iteration orders
        // lds_board rewrites; lds_gi/gh rewrites are behind the same barrier
    }
}

extern "C" void kernel_launch(void* const* d_in, const int* in_sizes, int n_in,
                              void* d_out, int out_size, void* d_ws, size_t ws_size,
                              hipStream_t stream)
{
    const float* x    = (const float*)d_in[0];
    const float* h0   = (const float*)d_in[1];
    const float* w_ih = (const float*)d_in[2];
    const float* w_hh = (const float*)d_in[3];
    const float* fc_w = (const float*)d_in[4];
    const float* fc_b = (const float*)d_in[5];
    float* out = (float*)d_out;
    u64* board = (u64*)d_ws;

    // clear board tags so every replay re-synchronizes from scratch
    // (out needs no memset: every element is written by exactly one plain store)
    hipMemsetAsync(d_ws, 0, BOARD_B, stream);

    void* args[] = { (void*)&x, (void*)&h0, (void*)&w_ih, (void*)&w_hh,
                     (void*)&fc_w, (void*)&fc_b, (void*)&out, (void*)&board };
    hipError_t err = hipLaunchCooperativeKernel((void*)gru_persistent,
                                                dim3(NGRP * WPG), dim3(BLOCK),
                                                args, 0, stream);
    if (err != hipSuccess) {
        (void)hipGetLastError();  // clear sticky error; plain launch (128 blocks
        // at 2 blocks/CU occupancy are trivially co-resident on 256 CUs)
        gru_persistent<<<dim3(NGRP * WPG), dim3(BLOCK), 0, stream>>>(
            x, h0, w_ih, w_hh, fc_w, fc_b, out, board);
    }
}

// Round 15
// 2642.289 us; speedup vs baseline: 1.4771x; 1.0926x over previous
//
#include <hip/hip_runtime.h>

typedef short bf16x8 __attribute__((ext_vector_type(8)));
typedef float f32x4  __attribute__((ext_vector_type(4)));
typedef unsigned int u32;
typedef unsigned long long u64;

constexpr int BB = 64;     // batch
constexpr int TT = 1024;   // seq len
constexpr int DD = 64;     // input dim
constexpr int HH = 512;    // hidden
constexpr int NGRP = 8;    // batch groups; group = wg & 7 -> same XCD under
                           // round-robin dispatch (heuristic only, not required)
constexpr int WPG  = 16;   // workgroups per group; wid = wg >> 3 owns slice wid
constexpr int MB   = 8;    // batch rows per group
constexpr int UPW  = 32;   // hidden units per wg
constexpr int BLOCK = 384; // 6 waves, one 16-col gate tile per wave

// tagged board: [2][NGRP][row 8][pair 256] u64; u64 = two tagged words
// word = (tag16 << 16) | bf16(h); pair index = wid*16+lp covers units (2lp,2lp+1)
constexpr size_t SLAB_U64  = (size_t)MB * 256;            // 2048 u64 per (buf,grp)
constexpr size_t BOARD_U64 = 2 * NGRP * SLAB_U64;         // 32768 u64
constexpr size_t BOARD_B   = BOARD_U64 * 8;               // 256 KB

__device__ __forceinline__ short f2bf(float f) {
    unsigned u = __builtin_bit_cast(unsigned, f);
    u = (u + 0x7FFFu + ((u >> 16) & 1u)) >> 16;   // round-to-nearest-even
    return (short)u;
}
__device__ __forceinline__ float bf2f(short s) {
    unsigned u = ((unsigned)(unsigned short)s) << 16;
    return __builtin_bit_cast(float, u);
}

// LDS board: [kk 16][row 8][LROW bytes]; unit ul of a slice-row at byte ul*2
constexpr int LROW = 80;
constexpr int LKK  = 656;   // 8*80 + 16 pad

__global__ __launch_bounds__(BLOCK, 2)
void gru_persistent(const float* __restrict__ x,
                    const float* __restrict__ h0,
                    const float* __restrict__ w_ih,
                    const float* __restrict__ w_hh,
                    const float* __restrict__ fc_w,
                    const float* __restrict__ fc_b,
                    float* __restrict__ out,
                    u64* __restrict__ board)
{
    const int wg   = blockIdx.x;     // 0..127
    const int gb   = wg & 7;         // group; == XCD id under round-robin dispatch
    const int wid  = wg >> 3;        // unit-wg 0..15 (owns k-slice kk == wid)
    const int tid  = threadIdx.x;
    const int wave = tid >> 6;       // 0..5
    const int lane = tid & 63;
    const int l15  = lane & 15;
    const int lhi  = lane >> 4;      // 0..3
    const int u0   = wid * UPW;

    // wave owns gate cols [wave*16, wave*16+16) of 96 = r|z|n x 32
    const int cloc = wave * 16 + l15;
    const int grow = (cloc >> 5) * HH + u0 + (cloc & 31);

    __shared__ char  lds_board[16 * LKK];   // staged h slab (A-operand + fc input)
    __shared__ float lds_gi[8][100];
    __shared__ float lds_gh[8][100];
    __shared__ float fcw_lds[HH];           // full fc_w row (f32)

    // ---- register-resident weights as MFMA B-frags, bf16 hi/lo split ----
    bf16x8 whh_hi[16], whh_lo[16];
#pragma unroll
    for (int kk = 0; kk < 16; ++kk) {
        const float* src = w_hh + (size_t)grow * HH + kk * 32 + lhi * 8;
        bf16x8 hi, lo;
#pragma unroll
        for (int i = 0; i < 8; ++i) {
            float w = src[i];
            short h16 = f2bf(w);
            hi[i] = h16; lo[i] = f2bf(w - bf2f(h16));
        }
        whh_hi[kk] = hi; whh_lo[kk] = lo;
    }
    bf16x8 wih_hi[2], wih_lo[2];
#pragma unroll
    for (int kk = 0; kk < 2; ++kk) {
        const float* src = w_ih + (size_t)grow * DD + kk * 32 + lhi * 8;
        bf16x8 hi, lo;
#pragma unroll
        for (int i = 0; i < 8; ++i) {
            float w = src[i];
            short h16 = f2bf(w);
            hi[i] = h16; lo[i] = f2bf(w - bf2f(h16));
        }
        wih_hi[kk] = hi; wih_lo[kk] = lo;
    }

    for (int i = tid; i < HH; i += BLOCK) fcw_lds[i] = fc_w[i];
    const float fcb = fc_b[0];

    // ---- init: hreg (2 f32/thread, tid<128) + board buf0 tagged (tag=1) ----
    float hreg0 = 0.f, hreg1 = 0.f;
    if (tid < 128) {
        int row = tid >> 4, lp = tid & 15;
        hreg0 = h0[(size_t)(gb * MB + row) * HH + (u0 + 2 * lp)];
        hreg1 = h0[(size_t)(gb * MB + row) * HH + (u0 + 2 * lp + 1)];
        u32 wa = (1u << 16) | (u32)(unsigned short)f2bf(hreg0);
        u32 wb = (1u << 16) | (u32)(unsigned short)f2bf(hreg1);
        u64* bw = board + (size_t)(0 * NGRP + gb) * SLAB_U64 + row * 256 + (wid * 16 + lp);
        __hip_atomic_store(bw, (u64)wa | ((u64)wb << 32),
                           __ATOMIC_RELAXED, __HIP_MEMORY_SCOPE_AGENT);
    }
    __syncthreads();

    const float* xrow = x + ((size_t)(gb * MB + (l15 & 7)) * TT) * DD + lhi * 8;

    // wave 5 (no publish duty) carries the fc-row snapshot across phases
    bf16x8 fc_hv = {0,0,0,0,0,0,0,0};
    auto fc_dot = [&](int tout) {
        float s = 0.f;
#pragma unroll
        for (int i = 0; i < 8; ++i)
            s += fmaxf(bf2f(fc_hv[i]), 0.f) * fcw_lds[lane * 8 + i];
#pragma unroll
        for (int off = 1; off < 64; off <<= 1) s += __shfl_xor(s, off, 64);
        if (lane == 0)
            out[(size_t)(gb * MB + wid) * TT + tout] = s + fcb;
    };

    for (int t = 0; t <= TT; ++t) {
        const int rbuf = t & 1, wbuf = rbuf ^ 1;

        // (a) issue the speculative board read FIRST (RT overlaps gi compute)
        u64 v[8];
        const u64* sp = board + (size_t)(rbuf * NGRP + gb) * SLAB_U64 + tid;
        if (tid < 256) {
#pragma unroll
            for (int i = 0; i < 8; ++i)
                v[i] = __hip_atomic_load(sp + (size_t)i * 256,
                                         __ATOMIC_RELAXED, __HIP_MEMORY_SCOPE_AGENT);
        }

        // (b) gi = x_t @ w_ih^T (skip on the epilogue iteration)
        f32x4 acc_gi = {0.f, 0.f, 0.f, 0.f};
        if (t < TT) {
            f32x4 gi_hi = {0.f,0.f,0.f,0.f}, gi_lo = {0.f,0.f,0.f,0.f};
#pragma unroll
            for (int kk = 0; kk < 2; ++kk) {
                const float* xs = xrow + (size_t)t * DD + kk * 32;
                const float4 v0 = *(const float4*)(xs);
                const float4 v1 = *(const float4*)(xs + 4);
                bf16x8 a;
                a[0] = f2bf(v0.x); a[1] = f2bf(v0.y); a[2] = f2bf(v0.z); a[3] = f2bf(v0.w);
                a[4] = f2bf(v1.x); a[5] = f2bf(v1.y); a[6] = f2bf(v1.z); a[7] = f2bf(v1.w);
                gi_hi = __builtin_amdgcn_mfma_f32_16x16x32_bf16(a, wih_hi[kk], gi_hi, 0, 0, 0);
                gi_lo = __builtin_amdgcn_mfma_f32_16x16x32_bf16(a, wih_lo[kk], gi_lo, 0, 0, 0);
            }
            acc_gi = gi_hi + gi_lo;
        }

        // (c) sound verify + bulk-reload spin (measured best protocol: R8->R11)
        if (tid < 256) {
            const u32 expTag = (u32)(t + 1) << 16;
            while (true) {
                u32 bad = 0;
#pragma unroll
                for (int i = 0; i < 8; ++i) {
                    u32 lo = (u32)v[i], hi = (u32)(v[i] >> 32);
                    bad |= ((lo ^ expTag) | (hi ^ expTag)) & 0xFFFF0000u;
                }
                if (!__any(bad != 0)) break;
#pragma unroll
                for (int i = 0; i < 8; ++i)
                    v[i] = __hip_atomic_load(sp + (size_t)i * 256,
                                             __ATOMIC_RELAXED, __HIP_MEMORY_SCOPE_AGENT);
            }
            // unpack to LDS: slice kk = tid>>4, pair lp = tid&15, rows i
            char* lb = lds_board + (tid >> 4) * LKK + (tid & 15) * 4;
#pragma unroll
            for (int i = 0; i < 8; ++i) {
                u32 d = __builtin_amdgcn_perm((u32)(v[i] >> 32), (u32)v[i], 0x05040100u);
                *(u32*)(lb + i * LROW) = d;
            }
        }
        __syncthreads();

        // (d) snapshot the fc row into wave-5 registers (~20 cy); the dot runs
        // AFTER the publish (g2), hidden under the next step's RT wait.
        // Safe by barrier order: next snapshot only after next (c) barrier,
        // which wave 5 cannot reach before finishing its dot.
        if (wave == 5 && wid < MB) {
            const char* lb = lds_board + (lane >> 2) * LKK + wid * LROW + (lane & 3) * 16;
            fc_hv = *(const bf16x8*)lb;
        }
        if (t == TT) {            // epilogue: only out[TT-1] remained
            if (wave == 5 && wid < MB) fc_dot(TT - 1);
            break;
        }

        // (e) gh MFMAs from LDS A-frags (rows dup for l15 in 8..15)
        f32x4 gh_hi = {0.f,0.f,0.f,0.f}, gh_lo = {0.f,0.f,0.f,0.f};
        {
            const char* la = lds_board + (l15 & 7) * LROW + lhi * 16;
#pragma unroll
            for (int kk = 0; kk < 16; ++kk) {
                bf16x8 a = *(const bf16x8*)(la + kk * LKK);
                gh_hi = __builtin_amdgcn_mfma_f32_16x16x32_bf16(a, whh_hi[kk], gh_hi, 0, 0, 0);
                gh_lo = __builtin_amdgcn_mfma_f32_16x16x32_bf16(a, whh_lo[kk], gh_lo, 0, 0, 0);
            }
        }
        f32x4 acc_gh = gh_hi + gh_lo;

        // (f) C/D -> LDS: col = cloc, row = lhi*4 + j (rows 0..7 only)
        if (lhi < 2) {
#pragma unroll
            for (int j = 0; j < 4; ++j) {
                int row = lhi * 4 + j;
                lds_gi[row][cloc] = acc_gi[j];
                lds_gh[row][cloc] = acc_gh[j];
            }
        }
        __syncthreads();

        // (g) gates + h update + immediate tagged publish (2 units/thread)
        if (tid < 128) {
            const u32 tagNew = (u32)(t + 2) << 16;
            int row = tid >> 4, lp = tid & 15;
            int uu0 = 2 * lp, uu1 = uu0 + 1;
            float hn01[2];
            float hp[2] = {hreg0, hreg1};
#pragma unroll
            for (int q = 0; q < 2; ++q) {
                int uu = uu0 + q;
                float gr  = lds_gi[row][uu]      + lds_gh[row][uu];
                float gz  = lds_gi[row][32 + uu] + lds_gh[row][32 + uu];
                float gin = lds_gi[row][64 + uu];
                float ghn = lds_gh[row][64 + uu];
                float r = 1.f / (1.f + __expf(-gr));
                float z = 1.f / (1.f + __expf(-gz));
                float vv = gin + r * ghn;
                vv = fminf(15.f, fmaxf(-15.f, vv));
                float e2 = __expf(-2.f * vv);
                float n = (1.f - e2) / (1.f + e2);           // tanh
                hn01[q] = (1.f - z) * n + z * hp[q];
            }
            hreg0 = hn01[0]; hreg1 = hn01[1];
            // publish FIRST (critical path for the 15 peers)
            u32 wa = tagNew | (u32)(unsigned short)f2bf(hn01[0]);
            u32 wb = tagNew | (u32)(unsigned short)f2bf(hn01[1]);
            u64* bw = board + (size_t)(wbuf * NGRP + gb) * SLAB_U64
                    + row * 256 + (wid * 16 + lp);
            __hip_atomic_store(bw, (u64)wa | ((u64)wb << 32),
                               __ATOMIC_RELAXED, __HIP_MEMORY_SCOPE_AGENT);
            if (t == TT - 1) {
                out[(size_t)BB * TT + (size_t)(gb * MB + row) * HH + (u0 + uu0)] = hn01[0];
                out[(size_t)BB * TT + (size_t)(gb * MB + row) * HH + (u0 + uu1)] = hn01[1];
            }
        }

        // (g2) deferred fc dot for out[t-1], in the RT shadow (wave 5 only)
        if (wave == 5 && wid < MB && t >= 1) fc_dot(t - 1);

        // no barrier needed here: (c)'s barrier in the next iteration orders
        // lds_board rewrites; lds_gi/gh rewrites are behind the same barrier
    }
}

extern "C" void kernel_launch(void* const* d_in, const int* in_sizes, int n_in,
                              void* d_out, int out_size, void* d_ws, size_t ws_size,
                              hipStream_t stream)
{
    const float* x    = (const float*)d_in[0];
    const float* h0   = (const float*)d_in[1];
    const float* w_ih = (const float*)d_in[2];
    const float* w_hh = (const float*)d_in[3];
    const float* fc_w = (const float*)d_in[4];
    const float* fc_b = (const float*)d_in[5];
    float* out = (float*)d_out;
    u64* board = (u64*)d_ws;

    // clear board tags so every replay re-synchronizes from scratch
    // (out needs no memset: every element is written by exactly one plain store)
    hipMemsetAsync(d_ws, 0, BOARD_B, stream);

    void* args[] = { (void*)&x, (void*)&h0, (void*)&w_ih, (void*)&w_hh,
                     (void*)&fc_w, (void*)&fc_b, (void*)&out, (void*)&board };
    hipError_t err = hipLaunchCooperativeKernel((void*)gru_persistent,
                                                dim3(NGRP * WPG), dim3(BLOCK),
                                                args, 0, stream);
    if (err != hipSuccess) {
        (void)hipGetLastError();  // clear sticky error; plain launch (128 blocks
        // at 2 blocks/CU occupancy are trivially co-resident on 256 CUs)
        gru_persistent<<<dim3(NGRP * WPG), dim3(BLOCK), 0, stream>>>(
            x, h0, w_ih, w_hh, fc_w, fc_b, out, board);
    }
}